// Round 10
// baseline (285.839 us; speedup 1.0000x reference)
//
#include <hip/hip_runtime.h>
#include <hip/hip_bf16.h>
#include <stdint.h>

#define IN_F 2048
#define OUT_F 8192
#define NROWS 2048
#define NS 32

typedef float  vf4  __attribute__((ext_vector_type(4)));
typedef short  vs4  __attribute__((ext_vector_type(4)));
typedef short  vs8  __attribute__((ext_vector_type(8)));
typedef float  vacc __attribute__((ext_vector_type(4)));
typedef unsigned int vu4 __attribute__((ext_vector_type(4)));

__device__ __forceinline__ short f2bf(float f) {
    return __builtin_bit_cast(short, __float2bfloat16(f));
}

__device__ __forceinline__ void gl2lds16(const void* g, void* l) {
    __builtin_amdgcn_global_load_lds((__attribute__((address_space(1))) void*)g,
                                     (__attribute__((address_space(3))) void*)l,
                                     16, 0, 0);
}

// K0: thr = thresholds*std  (+ dense_flops constant fill)
__global__ void __launch_bounds__(256) k_thr(const float* __restrict__ thresholds,
                                             const float* __restrict__ stdv,
                                             float* __restrict__ thr,
                                             float* __restrict__ dense) {
    int gid = blockIdx.x * 256 + threadIdx.x;
    int idx = gid * 4;
    vf4 t = *(const vf4*)(thresholds + idx);
    vf4 s = *(const vf4*)(stdv + (idx & (IN_F - 1)));
    *(vf4*)(thr + idx) = t * s;
    if (gid < NROWS / 4) {
        vf4 d = {16777216.0f, 16777216.0f, 16777216.0f, 16777216.0f};
        *(vf4*)(dense + gid * 4) = d;
    }
}

// K1: W[k][o] f32 -> Wt[o][k] bf16, pre-swizzled (byte ^ (o&7)<<4 per 128B k-tile).
__global__ void __launch_bounds__(256) k_wt(const float* __restrict__ W,
                                            char* __restrict__ Wt) {
    __shared__ float tile[64 * 64];          // [k][o] f32
    __shared__ unsigned int tbf[64 * 33];    // [o][k-pair], stride 33 uints
    int kt = blockIdx.x & 31;
    int ot = blockIdx.x >> 5;
    int t = threadIdx.x;
    int kbase = kt * 64, obase = ot * 64;
#pragma unroll
    for (int rr = 0; rr < 4; ++rr) {
        int r = rr * 16 + (t >> 4);
        int c = (t & 15) * 4;
        *(vf4*)(tile + r * 64 + c) =
            *(const vf4*)(W + (size_t)(kbase + r) * OUT_F + obase + c);
    }
    __syncthreads();
    int o = t & 63;
    int kc2 = (t >> 6) * 8;
#pragma unroll
    for (int j = 0; j < 8; ++j) {
        unsigned short lo = (unsigned short)f2bf(tile[(kc2 * 2 + 2 * j) * 64 + o]);
        unsigned short hi = (unsigned short)f2bf(tile[(kc2 * 2 + 2 * j + 1) * 64 + o]);
        tbf[o * 33 + kc2 + j] = (unsigned)lo | ((unsigned)hi << 16);
    }
    __syncthreads();
    int r = t >> 2, seg = t & 3;
    unsigned int d[8];
#pragma unroll
    for (int i = 0; i < 8; ++i) d[i] = tbf[r * 33 + seg * 8 + i];
    int s = (r & 7) << 4;
    char* rowp = Wt + (size_t)(obase + r) * 4096 + kt * 128;
    vu4 a = {d[0], d[1], d[2], d[3]};
    vu4 b = {d[4], d[5], d[6], d[7]};
    *(vu4*)(rowp + ((seg * 32) ^ s)) = a;
    *(vu4*)(rowp + ((seg * 32 + 16) ^ s)) = b;
}

// K2: pipelined per-stripe masked GEMM, 128x128 tile, BK=64, 4 waves.
// LDS: A 16K | B dbuf 2x16K = 48K -> target 3 blocks/CU. Coalesced x loads.
// mu/thr read per-step from global (L1/L2-hot, 16KB+8KB working set).
#define LDS_A  0
#define LDS_B  16384

struct XR { vf4 a[8]; };

__global__ void __launch_bounds__(256, 2) k_gemm(const float* __restrict__ x,
                                                 const char* __restrict__ Wt,
                                                 const float* __restrict__ bias,
                                                 const float* __restrict__ mu,
                                                 const float* __restrict__ thr,
                                                 float* __restrict__ y,
                                                 float* __restrict__ sparse) {
    __shared__ char lds[49152];
    __shared__ int scnt[128];

    int bid = blockIdx.x;
    int swz = (bid & 7) * 128 + (bid >> 3);   // XCD-contiguous, bijective
    int mt = swz >> 6, nt = swz & 63;         // mt-major per XCD: x stays L2-hot
    int m_base = mt * 128, n_base = nt * 128;
    const float* thrR = thr + (size_t)(nt >> 1) * IN_F;

    int t = threadIdx.x;
    int w = t >> 6, lane = t & 63;
    int lane16 = lane & 15, g = lane >> 4;
    int wm = w >> 1, wn = w & 1;

    // x mapping: instr v covers rows w*32 + v*4 + g, cols lane16*4..+3 (coalesced)
    int col4 = lane16 * 4;
    const float* xbase = x + (size_t)(m_base + w * 32 + g) * IN_F + col4;

    int brow = lane >> 3, bcol = (lane & 7) * 16;

    auto stageB = [&](int kt, int buf) {
#pragma unroll
        for (int q = 0; q < 4; ++q) {
            const char* src = Wt + (size_t)(n_base + (w * 4 + q) * 8 + brow) * 4096 +
                              kt * 128 + bcol;
            gl2lds16(src, lds + LDS_B + buf * 16384 + (w * 4 + q) * 1024);
        }
    };
    auto load_x = [&](int kt, XR& r) {
        const float* p = xbase + kt * 64;
#pragma unroll
        for (int v = 0; v < 8; ++v)
            r.a[v] = *(const vf4*)(p + (size_t)v * 4 * IN_F);
    };

    vacc acc[4][4];
#pragma unroll
    for (int i = 0; i < 4; ++i)
#pragma unroll
        for (int j = 0; j < 4; ++j)
            acc[i][j] = (vacc){0.f, 0.f, 0.f, 0.f};
    int cnt[8] = {0, 0, 0, 0, 0, 0, 0, 0};

    XR xa, xb;
    stageB(0, 0);
    load_x(0, xa);

    auto xform = [&](XR& r, vf4 mv, vf4 tv) {
#pragma unroll
        for (int v = 0; v < 8; ++v) {
            vf4 xv = r.a[v];
            vs4 o;
#pragma unroll
            for (int j = 0; j < 4; ++j) {
                float xm = xv[j] - mv[j];
                bool m = __builtin_fabsf(xm) > tv[j];
                cnt[v] += m ? 1 : 0;
                o[j] = f2bf(m ? xv[j] : mv[j]);
            }
            int row = w * 32 + v * 4 + g;
            *(vs4*)(lds + LDS_A + row * 128 + ((lane16 * 8) ^ ((row & 7) << 4))) = o;
        }
    };

    auto compute = [&](int buf) {
        const char* bbase = lds + LDS_B + buf * 16384;
#pragma unroll
        for (int ks = 0; ks < 2; ++ks) {
            vs8 af[4], bf[4];
#pragma unroll
            for (int i = 0; i < 4; ++i) {
                int row = wm * 64 + i * 16 + lane16;
                af[i] = *(const vs8*)(lds + LDS_A + row * 128 +
                                      ((ks * 64 + g * 16) ^ ((row & 7) << 4)));
                int col = wn * 64 + i * 16 + lane16;
                bf[i] = *(const vs8*)(bbase + col * 128 +
                                      ((ks * 64 + g * 16) ^ ((col & 7) << 4)));
            }
#pragma unroll
            for (int i = 0; i < 4; ++i)
#pragma unroll
                for (int j = 0; j < 4; ++j)
                    acc[i][j] = __builtin_amdgcn_mfma_f32_16x16x32_bf16(
                        af[i], bf[j], acc[i][j], 0, 0, 0);
        }
    };

    auto step = [&](int kt, XR& cur, XR& nxt) {
        bool pre = kt < 31;
        // mu/thr FIRST: their compiler wait (vmcnt<=12) never drains the prefetches
        vf4 mv = *(const vf4*)(mu + kt * 64 + col4);
        vf4 tv = *(const vf4*)(thrR + kt * 64 + col4);
        if (pre) load_x(kt + 1, nxt);          // coalesced prefetch, spans the iter
        __builtin_amdgcn_sched_barrier(0);
        __builtin_amdgcn_s_barrier();          // all waves done reading A / B[cur]
        __builtin_amdgcn_sched_barrier(0);
        if (pre) stageB(kt + 1, (kt + 1) & 1); // async, stays in flight
        xform(cur, mv, tv);                    // transform + count + ds_write A
        if (pre) asm volatile("s_waitcnt vmcnt(12)" ::: "memory");  // B(kt) landed
        else     asm volatile("s_waitcnt vmcnt(0)" ::: "memory");
        asm volatile("s_waitcnt lgkmcnt(0)" ::: "memory");          // A visible
        __builtin_amdgcn_s_barrier();
        __builtin_amdgcn_sched_barrier(0);
        compute(kt & 1);
    };

    for (int kt = 0; kt < 32; kt += 2) {
        step(kt, xa, xb);
        step(kt + 1, xb, xa);
    }

    // ---- epilogue: + bias
    float* yb = y + (size_t)(m_base + wm * 64) * OUT_F + n_base + wn * 64;
#pragma unroll
    for (int j = 0; j < 4; ++j) {
        int ng = j * 16 + lane16;
        float bv = bias[n_base + wn * 64 + ng];
#pragma unroll
        for (int i = 0; i < 4; ++i) {
            int mg = i * 16 + g * 4;
#pragma unroll
            for (int q = 0; q < 4; ++q)
                yb[(size_t)(mg + q) * OUT_F + ng] = acc[i][j][q] + bv;
        }
    }

    // ---- fused sparse_flops (exact: multiples of 256 <= 2^24)
    if (t < 128) scnt[t] = 0;
    __syncthreads();
    if ((nt & 1) == 0) {
#pragma unroll
        for (int v = 0; v < 8; ++v)
            atomicAdd(&scnt[w * 32 + v * 4 + g], cnt[v]);
        __syncthreads();
        if (t < 128)
            atomicAdd(sparse + m_base + t, 256.0f * (float)scnt[t]);
    }
}

extern "C" void kernel_launch(void* const* d_in, const int* in_sizes, int n_in,
                              void* d_out, int out_size, void* d_ws, size_t ws_size,
                              hipStream_t stream) {
    const float* x = (const float*)d_in[0];
    const float* W = (const float*)d_in[1];
    const float* bias = (const float*)d_in[2];
    const float* mu = (const float*)d_in[3];
    const float* stdv = (const float*)d_in[4];
    const float* thresholds = (const float*)d_in[5];

    float* y = (float*)d_out;
    float* dense = y + (size_t)NROWS * OUT_F;
    float* sparse = dense + NROWS;

    char* Wt = (char*)d_ws;                                   // 32 MiB bf16, swizzled
    float* thr = (float*)(Wt + (size_t)OUT_F * IN_F * 2);     // 256 KiB

    hipLaunchKernelGGL(k_thr, dim3((NS * IN_F) / 1024), dim3(256), 0, stream,
                       thresholds, stdv, thr, dense);
    hipLaunchKernelGGL(k_wt, dim3((IN_F / 64) * (OUT_F / 64)), dim3(256), 0, stream,
                       W, Wt);
    hipMemsetAsync(sparse, 0, NROWS * sizeof(float), stream);
    hipLaunchKernelGGL(k_gemm, dim3((NROWS / 128) * (OUT_F / 128)), dim3(256), 0,
                       stream, x, Wt, bias, mu, thr, y, sparse);
}

// Round 11
// 268.759 us; speedup vs baseline: 1.0636x; 1.0636x over previous
//
#include <hip/hip_runtime.h>
#include <hip/hip_bf16.h>
#include <stdint.h>

#define IN_F 2048
#define OUT_F 8192
#define NROWS 2048
#define NS 32

typedef float  vf4  __attribute__((ext_vector_type(4)));
typedef short  vs4  __attribute__((ext_vector_type(4)));
typedef short  vs8  __attribute__((ext_vector_type(8)));
typedef float  vacc __attribute__((ext_vector_type(4)));
typedef unsigned int vu4 __attribute__((ext_vector_type(4)));

__device__ __forceinline__ short f2bf(float f) {
    return __builtin_bit_cast(short, __float2bfloat16(f));
}

__device__ __forceinline__ void gl2lds16(const void* g, void* l) {
    __builtin_amdgcn_global_load_lds((__attribute__((address_space(1))) void*)g,
                                     (__attribute__((address_space(3))) void*)l,
                                     16, 0, 0);
}

// K0: thr = thresholds*std  (+ dense_flops constant fill)
__global__ void __launch_bounds__(256) k_thr(const float* __restrict__ thresholds,
                                             const float* __restrict__ stdv,
                                             float* __restrict__ thr,
                                             float* __restrict__ dense) {
    int gid = blockIdx.x * 256 + threadIdx.x;
    int idx = gid * 4;
    vf4 t = *(const vf4*)(thresholds + idx);
    vf4 s = *(const vf4*)(stdv + (idx & (IN_F - 1)));
    *(vf4*)(thr + idx) = t * s;
    if (gid < NROWS / 4) {
        vf4 d = {16777216.0f, 16777216.0f, 16777216.0f, 16777216.0f};
        *(vf4*)(dense + gid * 4) = d;
    }
}

// K1: W[k][o] f32 -> Wt[o][k] bf16, pre-swizzled (byte ^ (o&7)<<4 per 128B k-tile).
__global__ void __launch_bounds__(256) k_wt(const float* __restrict__ W,
                                            char* __restrict__ Wt) {
    __shared__ float tile[64 * 64];          // [k][o] f32
    __shared__ unsigned int tbf[64 * 33];    // [o][k-pair], stride 33 uints
    int kt = blockIdx.x & 31;
    int ot = blockIdx.x >> 5;
    int t = threadIdx.x;
    int kbase = kt * 64, obase = ot * 64;
#pragma unroll
    for (int rr = 0; rr < 4; ++rr) {
        int r = rr * 16 + (t >> 4);
        int c = (t & 15) * 4;
        *(vf4*)(tile + r * 64 + c) =
            *(const vf4*)(W + (size_t)(kbase + r) * OUT_F + obase + c);
    }
    __syncthreads();
    int o = t & 63;
    int kc2 = (t >> 6) * 8;
#pragma unroll
    for (int j = 0; j < 8; ++j) {
        unsigned short lo = (unsigned short)f2bf(tile[(kc2 * 2 + 2 * j) * 64 + o]);
        unsigned short hi = (unsigned short)f2bf(tile[(kc2 * 2 + 2 * j + 1) * 64 + o]);
        tbf[o * 33 + kc2 + j] = (unsigned)lo | ((unsigned)hi << 16);
    }
    __syncthreads();
    int r = t >> 2, seg = t & 3;
    unsigned int d[8];
#pragma unroll
    for (int i = 0; i < 8; ++i) d[i] = tbf[r * 33 + seg * 8 + i];
    int s = (r & 7) << 4;
    char* rowp = Wt + (size_t)(obase + r) * 4096 + kt * 128;
    vu4 a = {d[0], d[1], d[2], d[3]};
    vu4 b = {d[4], d[5], d[6], d[7]};
    *(vu4*)(rowp + ((seg * 32) ^ s)) = a;
    *(vu4*)(rowp + ((seg * 32 + 16) ^ s)) = b;
}

// K2: pipelined per-stripe masked GEMM, 128x128 tile, BK=64, 4 waves.
// XCD tiling: 2x4 rectangle grid; each XCD owns 8mt x 16nt (x 8MB + Wt 8MB),
// mt-major within XCD so the ~64-resident set is 8mt x 8nt (Wt 4MB = L2-fit).
#define LDS_A  0
#define LDS_B  16384

struct XR { vf4 a[8]; };

__global__ void __launch_bounds__(256, 2) k_gemm(const float* __restrict__ x,
                                                 const char* __restrict__ Wt,
                                                 const float* __restrict__ bias,
                                                 const float* __restrict__ mu,
                                                 const float* __restrict__ thr,
                                                 float* __restrict__ y,
                                                 float* __restrict__ sparse) {
    __shared__ char lds[49152];
    __shared__ int scnt[128];

    int bid = blockIdx.x;
    int xcd = bid & 7, idx = bid >> 3;
    int mt = (xcd >> 2) * 8 + (idx & 7);      // 8 mt per XCD, varies fastest
    int nt = (xcd & 3) * 16 + (idx >> 3);     // 16 nt per XCD
    int m_base = mt * 128, n_base = nt * 128;
    const float* thrR = thr + (size_t)(nt >> 1) * IN_F;

    int t = threadIdx.x;
    int w = t >> 6, lane = t & 63;
    int lane16 = lane & 15, g = lane >> 4;
    int wm = w >> 1, wn = w & 1;

    // x mapping: instr v covers rows w*32 + v*4 + g, cols lane16*4..+3 (coalesced)
    int col4 = lane16 * 4;
    const float* xbase = x + (size_t)(m_base + w * 32 + g) * IN_F + col4;

    int brow = lane >> 3, bcol = (lane & 7) * 16;

    auto stageB = [&](int kt, int buf) {
#pragma unroll
        for (int q = 0; q < 4; ++q) {
            const char* src = Wt + (size_t)(n_base + (w * 4 + q) * 8 + brow) * 4096 +
                              kt * 128 + bcol;
            gl2lds16(src, lds + LDS_B + buf * 16384 + (w * 4 + q) * 1024);
        }
    };
    auto load_x = [&](int kt, XR& r) {
        const float* p = xbase + kt * 64;
#pragma unroll
        for (int v = 0; v < 8; ++v)
            r.a[v] = *(const vf4*)(p + (size_t)v * 4 * IN_F);
    };

    vacc acc[4][4];
#pragma unroll
    for (int i = 0; i < 4; ++i)
#pragma unroll
        for (int j = 0; j < 4; ++j)
            acc[i][j] = (vacc){0.f, 0.f, 0.f, 0.f};
    int cnt[8] = {0, 0, 0, 0, 0, 0, 0, 0};

    XR xa, xb;
    stageB(0, 0);
    load_x(0, xa);

    auto xform = [&](XR& r, vf4 mv, vf4 tv) {
#pragma unroll
        for (int v = 0; v < 8; ++v) {
            vf4 xv = r.a[v];
            vs4 o;
#pragma unroll
            for (int j = 0; j < 4; ++j) {
                float xm = xv[j] - mv[j];
                bool m = __builtin_fabsf(xm) > tv[j];
                cnt[v] += m ? 1 : 0;
                o[j] = f2bf(m ? xv[j] : mv[j]);
            }
            int row = w * 32 + v * 4 + g;
            *(vs4*)(lds + LDS_A + row * 128 + ((lane16 * 8) ^ ((row & 7) << 4))) = o;
        }
    };

    auto compute = [&](int buf) {
        const char* bbase = lds + LDS_B + buf * 16384;
#pragma unroll
        for (int ks = 0; ks < 2; ++ks) {
            vs8 af[4], bf[4];
#pragma unroll
            for (int i = 0; i < 4; ++i) {
                int row = wm * 64 + i * 16 + lane16;
                af[i] = *(const vs8*)(lds + LDS_A + row * 128 +
                                      ((ks * 64 + g * 16) ^ ((row & 7) << 4)));
                int col = wn * 64 + i * 16 + lane16;
                bf[i] = *(const vs8*)(bbase + col * 128 +
                                      ((ks * 64 + g * 16) ^ ((col & 7) << 4)));
            }
#pragma unroll
            for (int i = 0; i < 4; ++i)
#pragma unroll
                for (int j = 0; j < 4; ++j)
                    acc[i][j] = __builtin_amdgcn_mfma_f32_16x16x32_bf16(
                        af[i], bf[j], acc[i][j], 0, 0, 0);
        }
    };

    auto step = [&](int kt, XR& cur, XR& nxt) {
        bool pre = kt < 31;
        // mu/thr FIRST: their compiler wait (vmcnt<=12) never drains the prefetches
        vf4 mv = *(const vf4*)(mu + kt * 64 + col4);
        vf4 tv = *(const vf4*)(thrR + kt * 64 + col4);
        if (pre) load_x(kt + 1, nxt);          // coalesced prefetch, spans the iter
        __builtin_amdgcn_sched_barrier(0);
        __builtin_amdgcn_s_barrier();          // all waves done reading A / B[cur]
        __builtin_amdgcn_sched_barrier(0);
        if (pre) stageB(kt + 1, (kt + 1) & 1); // async, stays in flight
        xform(cur, mv, tv);                    // transform + count + ds_write A
        if (pre) asm volatile("s_waitcnt vmcnt(12)" ::: "memory");  // B(kt) landed
        else     asm volatile("s_waitcnt vmcnt(0)" ::: "memory");
        asm volatile("s_waitcnt lgkmcnt(0)" ::: "memory");          // A visible
        __builtin_amdgcn_s_barrier();
        __builtin_amdgcn_sched_barrier(0);
        compute(kt & 1);
    };

    for (int kt = 0; kt < 32; kt += 2) {
        step(kt, xa, xb);
        step(kt + 1, xb, xa);
    }

    // ---- epilogue: + bias
    float* yb = y + (size_t)(m_base + wm * 64) * OUT_F + n_base + wn * 64;
#pragma unroll
    for (int j = 0; j < 4; ++j) {
        int ng = j * 16 + lane16;
        float bv = bias[n_base + wn * 64 + ng];
#pragma unroll
        for (int i = 0; i < 4; ++i) {
            int mg = i * 16 + g * 4;
#pragma unroll
            for (int q = 0; q < 4; ++q)
                yb[(size_t)(mg + q) * OUT_F + ng] = acc[i][j][q] + bv;
        }
    }

    // ---- fused sparse_flops (exact: multiples of 256 <= 2^24)
    if (t < 128) scnt[t] = 0;
    __syncthreads();
    if ((nt & 1) == 0) {
#pragma unroll
        for (int v = 0; v < 8; ++v)
            atomicAdd(&scnt[w * 32 + v * 4 + g], cnt[v]);
        __syncthreads();
        if (t < 128)
            atomicAdd(sparse + m_base + t, 256.0f * (float)scnt[t]);
    }
}

extern "C" void kernel_launch(void* const* d_in, const int* in_sizes, int n_in,
                              void* d_out, int out_size, void* d_ws, size_t ws_size,
                              hipStream_t stream) {
    const float* x = (const float*)d_in[0];
    const float* W = (const float*)d_in[1];
    const float* bias = (const float*)d_in[2];
    const float* mu = (const float*)d_in[3];
    const float* stdv = (const float*)d_in[4];
    const float* thresholds = (const float*)d_in[5];

    float* y = (float*)d_out;
    float* dense = y + (size_t)NROWS * OUT_F;
    float* sparse = dense + NROWS;

    char* Wt = (char*)d_ws;                                   // 32 MiB bf16, swizzled
    float* thr = (float*)(Wt + (size_t)OUT_F * IN_F * 2);     // 256 KiB

    hipLaunchKernelGGL(k_thr, dim3((NS * IN_F) / 1024), dim3(256), 0, stream,
                       thresholds, stdv, thr, dense);
    hipLaunchKernelGGL(k_wt, dim3((IN_F / 64) * (OUT_F / 64)), dim3(256), 0, stream,
                       W, Wt);
    hipMemsetAsync(sparse, 0, NROWS * sizeof(float), stream);
    hipLaunchKernelGGL(k_gemm, dim3((NROWS / 128) * (OUT_F / 128)), dim3(256), 0,
                       stream, x, Wt, bias, mu, thr, y, sparse);
}

// Round 12
// 240.984 us; speedup vs baseline: 1.1861x; 1.1153x over previous
//
#include <hip/hip_runtime.h>
#include <hip/hip_bf16.h>
#include <stdint.h>

#define IN_F 2048
#define OUT_F 8192
#define NROWS 2048
#define NS 32

typedef float  vf4  __attribute__((ext_vector_type(4)));
typedef short  vs4  __attribute__((ext_vector_type(4)));
typedef short  vs8  __attribute__((ext_vector_type(8)));
typedef float  vacc __attribute__((ext_vector_type(4)));
typedef unsigned int vu4 __attribute__((ext_vector_type(4)));

__device__ __forceinline__ short f2bf(float f) {
    return __builtin_bit_cast(short, __float2bfloat16(f));
}

__device__ __forceinline__ void gl2lds16(const void* g, void* l) {
    __builtin_amdgcn_global_load_lds((__attribute__((address_space(1))) void*)g,
                                     (__attribute__((address_space(3))) void*)l,
                                     16, 0, 0);
}

// K0: thr = thresholds*std  (+ dense_flops constant fill)
__global__ void __launch_bounds__(256) k_thr(const float* __restrict__ thresholds,
                                             const float* __restrict__ stdv,
                                             float* __restrict__ thr,
                                             float* __restrict__ dense) {
    int gid = blockIdx.x * 256 + threadIdx.x;
    int idx = gid * 4;
    vf4 t = *(const vf4*)(thresholds + idx);
    vf4 s = *(const vf4*)(stdv + (idx & (IN_F - 1)));
    *(vf4*)(thr + idx) = t * s;
    if (gid < NROWS / 4) {
        vf4 d = {16777216.0f, 16777216.0f, 16777216.0f, 16777216.0f};
        *(vf4*)(dense + gid * 4) = d;
    }
}

// K1: W[k][o] f32 -> Wt[o][k] bf16, pre-swizzled (byte ^ (o&7)<<4 per 128B k-tile).
__global__ void __launch_bounds__(256) k_wt(const float* __restrict__ W,
                                            char* __restrict__ Wt) {
    __shared__ float tile[64 * 64];          // [k][o] f32
    __shared__ unsigned int tbf[64 * 33];    // [o][k-pair], stride 33 uints
    int kt = blockIdx.x & 31;
    int ot = blockIdx.x >> 5;
    int t = threadIdx.x;
    int kbase = kt * 64, obase = ot * 64;
#pragma unroll
    for (int rr = 0; rr < 4; ++rr) {
        int r = rr * 16 + (t >> 4);
        int c = (t & 15) * 4;
        *(vf4*)(tile + r * 64 + c) =
            *(const vf4*)(W + (size_t)(kbase + r) * OUT_F + obase + c);
    }
    __syncthreads();
    int o = t & 63;
    int kc2 = (t >> 6) * 8;
#pragma unroll
    for (int j = 0; j < 8; ++j) {
        unsigned short lo = (unsigned short)f2bf(tile[(kc2 * 2 + 2 * j) * 64 + o]);
        unsigned short hi = (unsigned short)f2bf(tile[(kc2 * 2 + 2 * j + 1) * 64 + o]);
        tbf[o * 33 + kc2 + j] = (unsigned)lo | ((unsigned)hi << 16);
    }
    __syncthreads();
    int r = t >> 2, seg = t & 3;
    unsigned int d[8];
#pragma unroll
    for (int i = 0; i < 8; ++i) d[i] = tbf[r * 33 + seg * 8 + i];
    int s = (r & 7) << 4;
    char* rowp = Wt + (size_t)(obase + r) * 4096 + kt * 128;
    vu4 a = {d[0], d[1], d[2], d[3]};
    vu4 b = {d[4], d[5], d[6], d[7]};
    *(vu4*)(rowp + ((seg * 32) ^ s)) = a;
    *(vu4*)(rowp + ((seg * 32 + 16) ^ s)) = b;
}

// K2: wave-drift pipelined masked GEMM. 128x128 tile, BK=64, 4 waves.
// ONE barrier per K-step; A and B both double-buffered; per step:
//   stageB(t+1) | compute ks0(t) | xform(t+1)->A[nxt] | load x/mu/thr(t+2)
//   | compute ks1(t) | vmcnt(counted) | lgkmcnt | barrier
// Waves drift between barriers -> MFMA overlaps other waves' VALU.
#define LDS_A  0
#define LDS_B  32768

struct XR { vf4 a[8]; };

__global__ void __launch_bounds__(256, 2) k_gemm(const float* __restrict__ x,
                                                 const char* __restrict__ Wt,
                                                 const float* __restrict__ bias,
                                                 const float* __restrict__ mu,
                                                 const float* __restrict__ thr,
                                                 float* __restrict__ y,
                                                 float* __restrict__ sparse) {
    __shared__ char lds[66048];   // A dbuf 32K | B dbuf 32K | scnt 512 (tail reuse)

    int bid = blockIdx.x;
    int xcd = bid & 7, idx = bid >> 3;
    int mt = (xcd >> 2) * 8 + (idx & 7);      // 8 mt per XCD, varies fastest
    int nt = (xcd & 3) * 16 + (idx >> 3);     // 16 nt per XCD
    int m_base = mt * 128, n_base = nt * 128;
    const float* thrR = thr + (size_t)(nt >> 1) * IN_F;

    int t = threadIdx.x;
    int w = t >> 6, lane = t & 63;
    int lane16 = lane & 15, g = lane >> 4;
    int wm = w >> 1, wn = w & 1;

    int col4 = lane16 * 4;
    const float* xbase = x + (size_t)(m_base + w * 32 + g) * IN_F + col4;

    int brow = lane >> 3, bcol = (lane & 7) * 16;

    auto stageB = [&](int kt, int buf) {
#pragma unroll
        for (int q = 0; q < 4; ++q) {
            const char* src = Wt + (size_t)(n_base + (w * 4 + q) * 8 + brow) * 4096 +
                              kt * 128 + bcol;
            gl2lds16(src, lds + LDS_B + buf * 16384 + (w * 4 + q) * 1024);
        }
    };
    auto load_x = [&](int kt, XR& r) {
        const float* p = xbase + kt * 64;
#pragma unroll
        for (int v = 0; v < 8; ++v)
            r.a[v] = *(const vf4*)(p + (size_t)v * 4 * IN_F);
    };

    vacc acc[4][4];
#pragma unroll
    for (int i = 0; i < 4; ++i)
#pragma unroll
        for (int j = 0; j < 4; ++j)
            acc[i][j] = (vacc){0.f, 0.f, 0.f, 0.f};
    int cnt[8] = {0, 0, 0, 0, 0, 0, 0, 0};

    auto xform = [&](XR& r, vf4 mv, vf4 tv, int abuf) {
        char* abase = lds + LDS_A + abuf * 16384;
#pragma unroll
        for (int v = 0; v < 8; ++v) {
            vf4 xv = r.a[v];
            vs4 o;
#pragma unroll
            for (int j = 0; j < 4; ++j) {
                float xm = xv[j] - mv[j];
                bool m = __builtin_fabsf(xm) > tv[j];
                cnt[v] += m ? 1 : 0;
                o[j] = f2bf(m ? xv[j] : mv[j]);
            }
            int row = w * 32 + v * 4 + g;
            *(vs4*)(abase + row * 128 + ((lane16 * 8) ^ ((row & 7) << 4))) = o;
        }
    };

    auto compute_ks = [&](int ks, int buf) {
        const char* abase = lds + LDS_A + buf * 16384;
        const char* bbase = lds + LDS_B + buf * 16384;
        vs8 af[4], bf[4];
#pragma unroll
        for (int i = 0; i < 4; ++i) {
            int row = wm * 64 + i * 16 + lane16;
            af[i] = *(const vs8*)(abase + row * 128 +
                                  ((ks * 64 + g * 16) ^ ((row & 7) << 4)));
            int col = wn * 64 + i * 16 + lane16;
            bf[i] = *(const vs8*)(bbase + col * 128 +
                                  ((ks * 64 + g * 16) ^ ((col & 7) << 4)));
        }
#pragma unroll
        for (int i = 0; i < 4; ++i)
#pragma unroll
            for (int j = 0; j < 4; ++j)
                acc[i][j] = __builtin_amdgcn_mfma_f32_16x16x32_bf16(
                    af[i], bf[j], acc[i][j], 0, 0, 0);
    };

    XR xa, xb;
    vf4 m0, t0, m1, t1;

    // ---- prologue: x(0)+mv/tv(0) -> xform(0) -> A[0]; stageB(0); x(1)+mv/tv(1)
    load_x(0, xa);
    m0 = *(const vf4*)(mu + col4);
    t0 = *(const vf4*)(thrR + col4);
    stageB(0, 0);
    __builtin_amdgcn_sched_barrier(0);
    xform(xa, m0, t0, 0);                     // auto-wait drains x(0)/mv/tv, not stageB
    load_x(1, xb);
    m1 = *(const vf4*)(mu + 64 + col4);
    t1 = *(const vf4*)(thrR + 64 + col4);
    __builtin_amdgcn_sched_barrier(0);
    asm volatile("s_waitcnt vmcnt(10)" ::: "memory");   // stageB(0) landed
    asm volatile("s_waitcnt lgkmcnt(0)" ::: "memory");  // A[0] visible
    __builtin_amdgcn_sched_barrier(0);
    __builtin_amdgcn_s_barrier();
    __builtin_amdgcn_sched_barrier(0);

    auto step = [&](int kt, XR& xcur, XR& xnxt, vf4& mvc, vf4& tvc,
                    vf4& mvn, vf4& tvn) {
        int cur = kt & 1, nxt = cur ^ 1;
        if (kt < 31) stageB(kt + 1, nxt);     // issued FIRST: oldest vmcnt entries
        __builtin_amdgcn_sched_barrier(0);
        compute_ks(0, cur);
        if (kt < 31) xform(xcur, mvc, tvc, nxt);   // consumes x(kt+1), mv/tv(kt+1)
        if (kt < 30) {
            load_x(kt + 2, xnxt);
            mvn = *(const vf4*)(mu + (kt + 2) * 64 + col4);
            tvn = *(const vf4*)(thrR + (kt + 2) * 64 + col4);
        }
        __builtin_amdgcn_sched_barrier(0);
        compute_ks(1, cur);
        if (kt < 30)      asm volatile("s_waitcnt vmcnt(10)" ::: "memory");
        else if (kt < 31) asm volatile("s_waitcnt vmcnt(0)" ::: "memory");
        if (kt < 31) {
            asm volatile("s_waitcnt lgkmcnt(0)" ::: "memory");  // A[nxt] visible
            __builtin_amdgcn_sched_barrier(0);
            __builtin_amdgcn_s_barrier();
            __builtin_amdgcn_sched_barrier(0);
        }
    };

    for (int kt = 0; kt < 32; kt += 2) {
        step(kt, xb, xa, m1, t1, m0, t0);
        step(kt + 1, xa, xb, m0, t0, m1, t1);
    }

    // ---- epilogue: + bias
    float* yb = y + (size_t)(m_base + wm * 64) * OUT_F + n_base + wn * 64;
#pragma unroll
    for (int j = 0; j < 4; ++j) {
        int ng = j * 16 + lane16;
        float bv = bias[n_base + wn * 64 + ng];
#pragma unroll
        for (int i = 0; i < 4; ++i) {
            int mg = i * 16 + g * 4;
#pragma unroll
            for (int q = 0; q < 4; ++q)
                yb[(size_t)(mg + q) * OUT_F + ng] = acc[i][j][q] + bv;
        }
    }

    // ---- fused sparse_flops (exact: multiples of 256 <= 2^24)
    int* scnt = (int*)lds;                    // A[0] region dead by now
    __syncthreads();
    if (t < 128) scnt[t] = 0;
    __syncthreads();
    if ((nt & 1) == 0) {
#pragma unroll
        for (int v = 0; v < 8; ++v)
            atomicAdd(&scnt[w * 32 + v * 4 + g], cnt[v]);
        __syncthreads();
        if (t < 128)
            atomicAdd(sparse + m_base + t, 256.0f * (float)scnt[t]);
    }
}

extern "C" void kernel_launch(void* const* d_in, const int* in_sizes, int n_in,
                              void* d_out, int out_size, void* d_ws, size_t ws_size,
                              hipStream_t stream) {
    const float* x = (const float*)d_in[0];
    const float* W = (const float*)d_in[1];
    const float* bias = (const float*)d_in[2];
    const float* mu = (const float*)d_in[3];
    const float* stdv = (const float*)d_in[4];
    const float* thresholds = (const float*)d_in[5];

    float* y = (float*)d_out;
    float* dense = y + (size_t)NROWS * OUT_F;
    float* sparse = dense + NROWS;

    char* Wt = (char*)d_ws;                                   // 32 MiB bf16, swizzled
    float* thr = (float*)(Wt + (size_t)OUT_F * IN_F * 2);     // 256 KiB

    hipLaunchKernelGGL(k_thr, dim3((NS * IN_F) / 1024), dim3(256), 0, stream,
                       thresholds, stdv, thr, dense);
    hipLaunchKernelGGL(k_wt, dim3((IN_F / 64) * (OUT_F / 64)), dim3(256), 0, stream,
                       W, Wt);
    hipMemsetAsync(sparse, 0, NROWS * sizeof(float), stream);
    hipLaunchKernelGGL(k_gemm, dim3((NROWS / 128) * (OUT_F / 128)), dim3(256), 0,
                       stream, x, Wt, bias, mu, thr, y, sparse);
}